// Round 12
// baseline (175.322 us; speedup 1.0000x reference)
//
#include <hip/hip_runtime.h>

// SlidingKernelAttention: unfold(k=4,s=1) -> per-(b,c,patch-offset) attention
// over seq=256 tokens of dim=16 -> overlap-add fold.
// B=2, C=64, H=W=67, Ho=Wo=64, N = B*C*16 = 2048 independent sequences.
//
// R12 = R9 + register double-buffered kv prefetch in the main loop (full
// unroll). Evidence (R11): fused kernel measured 74.4us alone with pipes at
// 10/22% and minimal HBM traffic => the ~128 S->exp->PV chain-iters per wave
// run near-serially, each gated by a ~120cyc ds_read_b128 whose lgkmcnt wait
// lands right before first use. Prefetching tile t+1 while computing tile t
// gives each ds_read a full iteration of independent work to hide behind.
// Also confirmed (R11): the harness's 268MB d_ws poison fill (~43.4us) +
// d_out poison + graph gaps ≈ 50us are an unconditional floor in the timed
// window — present even when d_ws is never used.
//
// MFMA layout identity (R5-R11): 16x16 MFMA C/D layout == A-operand layout
// == B-operand layout, so projection MFMA results ARE attention operands:
//   K^T = Wk.X^T    -> A-frag of K      (for S^T = K.Q^T)
//   V   = X.Wv^T    -> A-frag of V^T    (for O^T = V^T.P^T)
//   Q^T = s.Wq.X^T  -> B-frag of Q^T
//   P^T = exp2(S^T) -> B-frag of P^T    (in-register)
// Register arrays statically indexed (R4 lesson). f16 vectors via
// v_cvt_pkrtz + bit_cast / shufflevector only (R8 lesson).

#define BATCH 2
#define CHAN 64
#define HWDIM 67
#define SEQ 256
#define DIM 16
#define NSEQ 2048            // BATCH*CHAN*16
#define PLANE 4096           // 64*64 elems per sequence
#define OUT_TOTAL (BATCH * CHAN * HWDIM * HWDIM)   // 574592
#define ATT_SCALE 0.70710678118654752f             // (DIM/HEADS)^-0.5
#define LOG2E 1.44269504088896340736f
#define HTILES 17            // ceil(67/4) output-row tiles per bc

typedef _Float16 half4 __attribute__((ext_vector_type(4)));
typedef _Float16 half8 __attribute__((ext_vector_type(8)));
typedef float float4v __attribute__((ext_vector_type(4)));
typedef __fp16 fp16x2 __attribute__((ext_vector_type(2)));
typedef unsigned int uint2v __attribute__((ext_vector_type(2)));

// 2x v_cvt_pkrtz + register-pair aliasing: zero insert/extract VALU.
static __device__ __forceinline__ half4 mk_half4(float a, float b, float c, float d) {
    fp16x2 lo = __builtin_amdgcn_cvt_pkrtz(a, b);
    fp16x2 hi = __builtin_amdgcn_cvt_pkrtz(c, d);
    uint2v u;
    u[0] = __builtin_bit_cast(unsigned int, lo);
    u[1] = __builtin_bit_cast(unsigned int, hi);
    return __builtin_bit_cast(half4, u);
}

static __device__ __forceinline__ half4 pack4(float4v c) {
    return mk_half4(c[0], c[1], c[2], c[3]);
}

__global__ __launch_bounds__(512, 4) void ska_attn_pass1(
    const float* __restrict__ x,      // [B, C, 67, 67]
    const float* __restrict__ w,      // [48, 16]
    _Float16* __restrict__ ao)        // [NSEQ, 64, 64] workspace (f16)
{
    // two sequences per block; per-sequence unioned buffer: [0:4] holds the
    // X-frag until tile t's projection, then [0:4]=K A-frag | [4:8]=V^T
    // A-frag. 2 x 16 KB.
    __shared__ __align__(16) _Float16 buf[2][16][64][8];

    const int half_id = threadIdx.x >> 8;           // which of the 2 sequences
    const int n  = blockIdx.x * 2 + half_id;
    const int p  = n & 15;
    const int bc = n >> 4;
    const int oi = p >> 2;
    const int oj = p & 3;

    const int s   = threadIdx.x & 255;    // token id 0..255 within sequence
    const int ph  = s >> 2;
    const int pw0 = (s & 3) * DIM;

    // stage this token's 16 features as f16 X-fragment (wave-private tiles:
    // kt = s>>4 lies in [4*wave, 4*wave+4))
    const float* xrow = x + ((size_t)bc * HWDIM + (ph + oi)) * HWDIM + pw0 + oj;
    const int kt = s >> 4, kk = s & 15;
#pragma unroll
    for (int dh = 0; dh < 4; ++dh) {
        const half4 h = mk_half4(xrow[4 * dh + 0], xrow[4 * dh + 1],
                                 xrow[4 * dh + 2], xrow[4 * dh + 3]);
        *(half4*)&buf[half_id][kt][kk + 16 * dh][0] = h;
    }

    const int wave = (threadIdx.x >> 6) & 3;   // wave within this sequence
    const int lane = threadIdx.x & 63;
    const int o = lane & 15;      // weight output row held by this lane
    const int g = lane >> 4;      // k-group

    // weight fragments straight from global (3 KB, L1-resident)
    const float4 wq4 = *(const float4*)(w + ( 0 + o) * DIM + 4 * g);
    const float4 wk4 = *(const float4*)(w + (16 + o) * DIM + 4 * g);
    const float4 wv4 = *(const float4*)(w + (32 + o) * DIM + 4 * g);
    const half4 wqf = mk_half4(wq4.x * (ATT_SCALE * LOG2E), wq4.y * (ATT_SCALE * LOG2E),
                               wq4.z * (ATT_SCALE * LOG2E), wq4.w * (ATT_SCALE * LOG2E));
    const half4 wkf = mk_half4(wk4.x, wk4.y, wk4.z, wk4.w);
    const half4 wvf = mk_half4(wv4.x, wv4.y, wv4.z, wv4.w);

    const float4v zf = (float4v){0.f, 0.f, 0.f, 0.f};

    // projection: wave w handles tiles 4w..4w+3 (the tiles it staged — no
    // barrier needed; xF portion of buf[t] is dead after kv write of tile t).
    half4 qfr[4];
#pragma unroll
    for (int u = 0; u < 4; ++u) {
        const int t = 4 * wave + u;
        const half4 xf = *(const half4*)&buf[half_id][t][lane][0];
        const half4 kf = pack4(__builtin_amdgcn_mfma_f32_16x16x16f16(wkf, xf, zf, 0, 0, 0));
        const half4 vf = pack4(__builtin_amdgcn_mfma_f32_16x16x16f16(xf, wvf, zf, 0, 0, 0));
        const half8 kv = __builtin_shufflevector(kf, vf, 0, 1, 2, 3, 4, 5, 6, 7);
        *(half8*)&buf[half_id][t][lane][0] = kv;
        qfr[u] = pack4(__builtin_amdgcn_mfma_f32_16x16x16f16(wqf, xf, zf, 0, 0, 0));
    }
    __syncthreads();   // kv frags ready (the only barrier; syncs both halves)

    float4v oacc[4];
    float lpart[4];
#pragma unroll
    for (int j = 0; j < 4; ++j) {
        oacc[j] = zf;
        lpart[j] = 0.f;
    }

    // main loop, register double-buffered: tile t+1's kv is in flight while
    // tile t computes — the ds_read's ~120cyc latency hides behind a full
    // iteration (~300cyc) of independent chain work.
    half8 kvcur = *(const half8*)&buf[half_id][0][lane][0];
#pragma unroll
    for (int t = 0; t < 16; ++t) {
        half8 kvnext;
        if (t < 15) kvnext = *(const half8*)&buf[half_id][t + 1][lane][0];
        const half4 kf = __builtin_shufflevector(kvcur, kvcur, 0, 1, 2, 3);
        const half4 vf = __builtin_shufflevector(kvcur, kvcur, 4, 5, 6, 7);
#pragma unroll
        for (int j = 0; j < 4; ++j) {
            float4v sfr = __builtin_amdgcn_mfma_f32_16x16x16f16(kf, qfr[j], zf, 0, 0, 0);
            const float p0 = __builtin_amdgcn_exp2f(sfr[0]);
            const float p1 = __builtin_amdgcn_exp2f(sfr[1]);
            const float p2 = __builtin_amdgcn_exp2f(sfr[2]);
            const float p3 = __builtin_amdgcn_exp2f(sfr[3]);
            lpart[j] += (p0 + p1) + (p2 + p3);
            const half4 pb = mk_half4(p0, p1, p2, p3);
            oacc[j] = __builtin_amdgcn_mfma_f32_16x16x16f16(vf, pb, oacc[j], 0, 0, 0);
        }
        if (t < 15) kvcur = kvnext;
    }

    // softmax denom: sum lane groups {qq, qq+16, qq+32, qq+48}; store O^T frag
#pragma unroll
    for (int j = 0; j < 4; ++j) {
        float lj = lpart[j];
        lj += __shfl_xor(lj, 16, 64);
        lj += __shfl_xor(lj, 32, 64);
        const float rl = 1.f / lj;
        const int query = (4 * wave + j) * 16 + (lane & 15);
        const half4 hv = mk_half4(oacc[j][0] * rl, oacc[j][1] * rl,
                                  oacc[j][2] * rl, oacc[j][3] * rl);
        *(half4*)(ao + (size_t)n * PLANE + query * DIM + 4 * g) = hv;
    }
}

// pass 2: block = (bc, 4 output rows). Stage the 16 planes x 4 rows of ao
// this block needs (8 KB) with coalesced 16B loads, then each pixel sums 16
// LDS halves. sA[pl][hh] holds ao[bc*16+pl][h0+hh - (pl>>2)][0:64] (0 if OOB).
__global__ __launch_bounds__(256) void ska_fold_pass2(
    const _Float16* __restrict__ ao,  // [NSEQ, 64, 64] f16
    float* __restrict__ out)          // [B, C, 67, 67]
{
    __shared__ __align__(16) _Float16 sA[16][4][64];   // 8 KB

    const int blk = blockIdx.x;
    const int h0  = (blk % HTILES) * 4;
    const int bc  = blk / HTILES;
    const int tid = threadIdx.x;

    // stage: 4096 halves, 16 per thread as 2x half8
    {
        const int pl = tid >> 4;           // plane 0..15
        const int hh = (tid >> 2) & 3;     // local row 0..3
        const int pw = (tid & 3) * 16;     // col base 0/16/32/48
        const int i  = pl >> 2;
        const int prow = h0 + hh - i;      // source plane row
        half8 v0, v1;
        if (prow >= 0 && prow < 64) {
            const _Float16* src = ao + ((size_t)(bc * 16 + pl)) * PLANE + prow * 64 + pw;
            v0 = *(const half8*)src;
            v1 = *(const half8*)(src + 8);
        } else {
            const half8 z = (half8)(_Float16)0.f;
            v0 = z; v1 = z;
        }
        *(half8*)&sA[pl][hh][pw]     = v0;
        *(half8*)&sA[pl][hh][pw + 8] = v1;
    }
    __syncthreads();

    for (int px = tid; px < 4 * HWDIM; px += 256) {
        const int hh = px / HWDIM;
        const int ww = px % HWDIM;
        const int h  = h0 + hh;
        if (h >= HWDIM) continue;
        float acc = 0.f;
#pragma unroll
        for (int i = 0; i < 4; ++i) {
#pragma unroll
            for (int j = 0; j < 4; ++j) {
                const int pw = ww - j;
                if (pw < 0 || pw >= 64) continue;
                acc += (float)sA[i * 4 + j][hh][pw];
            }
        }
        out[((size_t)bc * HWDIM + h) * HWDIM + ww] = acc;
    }
}

// ---- fallback (atomic fold) if workspace is too small ----
__global__ __launch_bounds__(256) void ska_attn_atomic(
    const float* __restrict__ x, const float* __restrict__ w,
    float* __restrict__ out)
{
    __shared__ float sw[3 * DIM * DIM];
    __shared__ float sk[SEQ][DIM];
    __shared__ float sv[SEQ][DIM];

    const int n = blockIdx.x, p = n & 15, bc = n >> 4, oi = p >> 2, oj = p & 3;
    const int s = threadIdx.x, ph = s >> 2, pw0 = (s & 3) * DIM;

#pragma unroll
    for (int r = 0; r < 3; ++r) sw[r * 256 + s] = w[r * 256 + s];

    const float* xrow = x + ((size_t)bc * HWDIM + (ph + oi)) * HWDIM + pw0 + oj;
    float xr[DIM];
#pragma unroll
    for (int d = 0; d < DIM; ++d) xr[d] = xrow[d];
    __syncthreads();

    float q[DIM];
#pragma unroll
    for (int o = 0; o < DIM; ++o) {
        float aq = 0.f, ak = 0.f, av = 0.f;
#pragma unroll
        for (int d = 0; d < DIM; ++d) {
            aq += xr[d] * sw[o * DIM + d];
            ak += xr[d] * sw[(DIM + o) * DIM + d];
            av += xr[d] * sw[(2 * DIM + o) * DIM + d];
        }
        q[o] = aq * ATT_SCALE; sk[s][o] = ak; sv[s][o] = av;
    }
    __syncthreads();

    float l = 0.f, acc[DIM];
#pragma unroll
    for (int d = 0; d < DIM; ++d) acc[d] = 0.f;
    for (int t = 0; t < SEQ; ++t) {
        float sc = 0.f;
#pragma unroll
        for (int d = 0; d < DIM; ++d) sc += q[d] * sk[t][d];
        const float pe = __expf(sc);
        l += pe;
#pragma unroll
        for (int d = 0; d < DIM; ++d) acc[d] += pe * sv[t][d];
    }
    const float rl = 1.f / l;
    float* obase = out + ((size_t)bc * HWDIM + (ph + oi)) * HWDIM + pw0 + oj;
#pragma unroll
    for (int d = 0; d < DIM; ++d) atomicAdd(&obase[d], acc[d] * rl);
}

extern "C" void kernel_launch(void* const* d_in, const int* in_sizes, int n_in,
                              void* d_out, int out_size, void* d_ws, size_t ws_size,
                              hipStream_t stream) {
    const float* x = (const float*)d_in[0];
    const float* w = (const float*)d_in[1];
    float* out = (float*)d_out;

    const size_t need = (size_t)NSEQ * PLANE * sizeof(_Float16);   // 16.8 MB
    if (ws_size >= need) {
        _Float16* ao = (_Float16*)d_ws;
        ska_attn_pass1<<<NSEQ / 2, 512, 0, stream>>>(x, w, ao);
        ska_fold_pass2<<<BATCH * CHAN * HTILES, 256, 0, stream>>>(ao, out);
    } else {
        (void)hipMemsetAsync(out, 0, (size_t)out_size * sizeof(float), stream);
        ska_attn_atomic<<<NSEQ, 256, 0, stream>>>(x, w, out);
    }
}

// Round 13
// 87.170 us; speedup vs baseline: 2.0113x; 2.0113x over previous
//
#include <hip/hip_runtime.h>

// SlidingKernelAttention: unfold(k=4,s=1) -> per-(b,c,patch-offset) attention
// over seq=256 tokens of dim=16 -> overlap-add fold.
// B=2, C=64, H=W=67, Ho=Wo=64, N = B*C*16 = 2048 independent sequences.
//
// R13: register-resident K/V. Each wave projects ALL 16 k-tiles itself
// (48 proj MFMAs) into kfr[16]/vfr[16] (64 VGPRs); the 256-key main loop
// has ZERO LDS reads (R12's spill disaster came from trying to HIDE the
// per-tile ds_read via a rotating buffer — this removes the ds_read).
// Both loops fully unrolled, all register-array indices compile-time
// static (R4 lesson). LDS = 8 KB xF only; one barrier.
// launch_bounds(256,4): 128-VGPR budget for ~115 live regs (spill guard).
// Fixed harness floor ~50us in the timed window (268MB d_ws poison fill
// ~43us + d_out poison + graph gaps) — measured via R11 (74.4us kernel ->
// 124.7 total). R9 baseline: 85.1 total => controllable ~35us.
//
// MFMA layout identity (R5-R12): 16x16 MFMA C/D layout == A-operand layout
// == B-operand layout, so projection MFMA results ARE attention operands:
//   K^T = Wk.X^T    -> A-frag of K      (for S^T = K.Q^T)
//   V   = X.Wv^T    -> A-frag of V^T    (for O^T = V^T.P^T)
//   Q^T = s.Wq.X^T  -> B-frag of Q^T
//   P^T = exp2(S^T) -> B-frag of P^T    (in-register)
// f16 vectors via v_cvt_pkrtz + bit_cast / shufflevector only (R8 lesson).

#define BATCH 2
#define CHAN 64
#define HWDIM 67
#define SEQ 256
#define DIM 16
#define NSEQ 2048            // BATCH*CHAN*16
#define PLANE 4096           // 64*64 elems per sequence
#define OUT_TOTAL (BATCH * CHAN * HWDIM * HWDIM)   // 574592
#define ATT_SCALE 0.70710678118654752f             // (DIM/HEADS)^-0.5
#define LOG2E 1.44269504088896340736f
#define HTILES 17            // ceil(67/4) output-row tiles per bc

typedef _Float16 half4 __attribute__((ext_vector_type(4)));
typedef _Float16 half8 __attribute__((ext_vector_type(8)));
typedef float float4v __attribute__((ext_vector_type(4)));
typedef __fp16 fp16x2 __attribute__((ext_vector_type(2)));
typedef unsigned int uint2v __attribute__((ext_vector_type(2)));

// 2x v_cvt_pkrtz + register-pair aliasing: zero insert/extract VALU.
static __device__ __forceinline__ half4 mk_half4(float a, float b, float c, float d) {
    fp16x2 lo = __builtin_amdgcn_cvt_pkrtz(a, b);
    fp16x2 hi = __builtin_amdgcn_cvt_pkrtz(c, d);
    uint2v u;
    u[0] = __builtin_bit_cast(unsigned int, lo);
    u[1] = __builtin_bit_cast(unsigned int, hi);
    return __builtin_bit_cast(half4, u);
}

static __device__ __forceinline__ half4 pack4(float4v c) {
    return mk_half4(c[0], c[1], c[2], c[3]);
}

__global__ __launch_bounds__(256, 4) void ska_attn_pass1(
    const float* __restrict__ x,      // [B, C, 67, 67]
    const float* __restrict__ w,      // [48, 16]
    _Float16* __restrict__ ao)        // [NSEQ, 64, 64] workspace (f16)
{
    __shared__ __align__(16) _Float16 xF[16][64][4];   // X-tile frags, 8 KB

    const int n  = blockIdx.x;
    const int p  = n & 15;
    const int bc = n >> 4;
    const int oi = p >> 2;
    const int oj = p & 3;

    const int s   = threadIdx.x;          // token id 0..255
    const int ph  = s >> 2;
    const int pw0 = (s & 3) * DIM;

    // stage this token's 16 features as f16 X-fragment
    const float* xrow = x + ((size_t)bc * HWDIM + (ph + oi)) * HWDIM + pw0 + oj;
    const int kt = s >> 4, kk = s & 15;
#pragma unroll
    for (int dh = 0; dh < 4; ++dh) {
        const half4 h = mk_half4(xrow[4 * dh + 0], xrow[4 * dh + 1],
                                 xrow[4 * dh + 2], xrow[4 * dh + 3]);
        *(half4*)&xF[kt][kk + 16 * dh][0] = h;
    }

    const int wave = s >> 6;
    const int lane = s & 63;
    const int o = lane & 15;      // weight output row held by this lane
    const int g = lane >> 4;      // k-group

    // weight fragments straight from global (3 KB, L1-resident)
    const float4 wq4 = *(const float4*)(w + ( 0 + o) * DIM + 4 * g);
    const float4 wk4 = *(const float4*)(w + (16 + o) * DIM + 4 * g);
    const float4 wv4 = *(const float4*)(w + (32 + o) * DIM + 4 * g);
    const half4 wqf = mk_half4(wq4.x * (ATT_SCALE * LOG2E), wq4.y * (ATT_SCALE * LOG2E),
                               wq4.z * (ATT_SCALE * LOG2E), wq4.w * (ATT_SCALE * LOG2E));
    const half4 wkf = mk_half4(wk4.x, wk4.y, wk4.z, wk4.w);
    const half4 wvf = mk_half4(wv4.x, wv4.y, wv4.z, wv4.w);

    const float4v zf = (float4v){0.f, 0.f, 0.f, 0.f};

    __syncthreads();   // xF ready (the only barrier)

    // projection: ALL 16 K/V fragments into registers (static indices only)
    half4 kfr[16], vfr[16];
#pragma unroll
    for (int t = 0; t < 16; ++t) {
        const half4 xf = *(const half4*)&xF[t][lane][0];
        kfr[t] = pack4(__builtin_amdgcn_mfma_f32_16x16x16f16(wkf, xf, zf, 0, 0, 0));
        vfr[t] = pack4(__builtin_amdgcn_mfma_f32_16x16x16f16(xf, wvf, zf, 0, 0, 0));
    }
    // this wave's 4 Q^T B-fragments
    half4 qfr[4];
#pragma unroll
    for (int u = 0; u < 4; ++u) {
        const half4 xf = *(const half4*)&xF[4 * wave + u][lane][0];
        qfr[u] = pack4(__builtin_amdgcn_mfma_f32_16x16x16f16(wqf, xf, zf, 0, 0, 0));
    }

    float4v oacc[4];
    float lpart[4];
#pragma unroll
    for (int j = 0; j < 4; ++j) {
        oacc[j] = zf;
        lpart[j] = 0.f;
    }

    // main loop: pure register MFMA + exp2 — no LDS, no rotation.
#pragma unroll
    for (int t = 0; t < 16; ++t) {
        const half4 kf = kfr[t];
        const half4 vf = vfr[t];
#pragma unroll
        for (int j = 0; j < 4; ++j) {
            float4v sfr = __builtin_amdgcn_mfma_f32_16x16x16f16(kf, qfr[j], zf, 0, 0, 0);
            const float p0 = __builtin_amdgcn_exp2f(sfr[0]);
            const float p1 = __builtin_amdgcn_exp2f(sfr[1]);
            const float p2 = __builtin_amdgcn_exp2f(sfr[2]);
            const float p3 = __builtin_amdgcn_exp2f(sfr[3]);
            lpart[j] += (p0 + p1) + (p2 + p3);
            const half4 pb = mk_half4(p0, p1, p2, p3);
            oacc[j] = __builtin_amdgcn_mfma_f32_16x16x16f16(vf, pb, oacc[j], 0, 0, 0);
        }
    }

    // softmax denom: sum lane groups {qq, qq+16, qq+32, qq+48}; store O^T frag
#pragma unroll
    for (int j = 0; j < 4; ++j) {
        float lj = lpart[j];
        lj += __shfl_xor(lj, 16, 64);
        lj += __shfl_xor(lj, 32, 64);
        const float rl = 1.f / lj;
        const int query = (4 * wave + j) * 16 + (lane & 15);
        const half4 hv = mk_half4(oacc[j][0] * rl, oacc[j][1] * rl,
                                  oacc[j][2] * rl, oacc[j][3] * rl);
        *(half4*)(ao + (size_t)n * PLANE + query * DIM + 4 * g) = hv;
    }
}

// pass 2: block = (bc, 4 output rows). Stage the 16 planes x 4 rows of ao
// this block needs (8 KB) with coalesced 16B loads, then each pixel sums 16
// LDS halves. sA[pl][hh] holds ao[bc*16+pl][h0+hh - (pl>>2)][0:64] (0 if OOB).
__global__ __launch_bounds__(256) void ska_fold_pass2(
    const _Float16* __restrict__ ao,  // [NSEQ, 64, 64] f16
    float* __restrict__ out)          // [B, C, 67, 67]
{
    __shared__ __align__(16) _Float16 sA[16][4][64];   // 8 KB

    const int blk = blockIdx.x;
    const int h0  = (blk % HTILES) * 4;
    const int bc  = blk / HTILES;
    const int tid = threadIdx.x;

    // stage: 4096 halves, 16 per thread as 2x half8
    {
        const int pl = tid >> 4;           // plane 0..15
        const int hh = (tid >> 2) & 3;     // local row 0..3
        const int pw = (tid & 3) * 16;     // col base 0/16/32/48
        const int i  = pl >> 2;
        const int prow = h0 + hh - i;      // source plane row
        half8 v0, v1;
        if (prow >= 0 && prow < 64) {
            const _Float16* src = ao + ((size_t)(bc * 16 + pl)) * PLANE + prow * 64 + pw;
            v0 = *(const half8*)src;
            v1 = *(const half8*)(src + 8);
        } else {
            const half8 z = (half8)(_Float16)0.f;
            v0 = z; v1 = z;
        }
        *(half8*)&sA[pl][hh][pw]     = v0;
        *(half8*)&sA[pl][hh][pw + 8] = v1;
    }
    __syncthreads();

    for (int px = tid; px < 4 * HWDIM; px += 256) {
        const int hh = px / HWDIM;
        const int ww = px % HWDIM;
        const int h  = h0 + hh;
        if (h >= HWDIM) continue;
        float acc = 0.f;
#pragma unroll
        for (int i = 0; i < 4; ++i) {
#pragma unroll
            for (int j = 0; j < 4; ++j) {
                const int pw = ww - j;
                if (pw < 0 || pw >= 64) continue;
                acc += (float)sA[i * 4 + j][hh][pw];
            }
        }
        out[((size_t)bc * HWDIM + h) * HWDIM + ww] = acc;
    }
}

// ---- fallback (atomic fold) if workspace is too small ----
__global__ __launch_bounds__(256) void ska_attn_atomic(
    const float* __restrict__ x, const float* __restrict__ w,
    float* __restrict__ out)
{
    __shared__ float sw[3 * DIM * DIM];
    __shared__ float sk[SEQ][DIM];
    __shared__ float sv[SEQ][DIM];

    const int n = blockIdx.x, p = n & 15, bc = n >> 4, oi = p >> 2, oj = p & 3;
    const int s = threadIdx.x, ph = s >> 2, pw0 = (s & 3) * DIM;

#pragma unroll
    for (int r = 0; r < 3; ++r) sw[r * 256 + s] = w[r * 256 + s];

    const float* xrow = x + ((size_t)bc * HWDIM + (ph + oi)) * HWDIM + pw0 + oj;
    float xr[DIM];
#pragma unroll
    for (int d = 0; d < DIM; ++d) xr[d] = xrow[d];
    __syncthreads();

    float q[DIM];
#pragma unroll
    for (int o = 0; o < DIM; ++o) {
        float aq = 0.f, ak = 0.f, av = 0.f;
#pragma unroll
        for (int d = 0; d < DIM; ++d) {
            aq += xr[d] * sw[o * DIM + d];
            ak += xr[d] * sw[(DIM + o) * DIM + d];
            av += xr[d] * sw[(2 * DIM + o) * DIM + d];
        }
        q[o] = aq * ATT_SCALE; sk[s][o] = ak; sv[s][o] = av;
    }
    __syncthreads();

    float l = 0.f, acc[DIM];
#pragma unroll
    for (int d = 0; d < DIM; ++d) acc[d] = 0.f;
    for (int t = 0; t < SEQ; ++t) {
        float sc = 0.f;
#pragma unroll
        for (int d = 0; d < DIM; ++d) sc += q[d] * sk[t][d];
        const float pe = __expf(sc);
        l += pe;
#pragma unroll
        for (int d = 0; d < DIM; ++d) acc[d] += pe * sv[t][d];
    }
    const float rl = 1.f / l;
    float* obase = out + ((size_t)bc * HWDIM + (ph + oi)) * HWDIM + pw0 + oj;
#pragma unroll
    for (int d = 0; d < DIM; ++d) atomicAdd(&obase[d], acc[d] * rl);
}

extern "C" void kernel_launch(void* const* d_in, const int* in_sizes, int n_in,
                              void* d_out, int out_size, void* d_ws, size_t ws_size,
                              hipStream_t stream) {
    const float* x = (const float*)d_in[0];
    const float* w = (const float*)d_in[1];
    float* out = (float*)d_out;

    const size_t need = (size_t)NSEQ * PLANE * sizeof(_Float16);   // 16.8 MB
    if (ws_size >= need) {
        _Float16* ao = (_Float16*)d_ws;
        ska_attn_pass1<<<NSEQ, 256, 0, stream>>>(x, w, ao);
        ska_fold_pass2<<<BATCH * CHAN * HTILES, 256, 0, stream>>>(ao, out);
    } else {
        (void)hipMemsetAsync(out, 0, (size_t)out_size * sizeof(float), stream);
        ska_attn_atomic<<<NSEQ, 256, 0, stream>>>(x, w, out);
    }
}